// Round 7
// baseline (657.973 us; speedup 1.0000x reference)
//
#include <hip/hip_runtime.h>
#include <hip/hip_fp16.h>

// NLSPN deformable propagation, B=4, H=480, W=640, 18 steps.
// Round 12: stop fighting the register allocator -- descriptors go to LDS.
//   R9-R11: three escalations (full unroll, asm TOUCH, waves_per_eu(2,2))
//   all left VGPR_Count at exactly 128 with FETCH=1.64GB: the gfx950
//   backend refuses >128 arch-VGPRs here and spills the 140 pinned words
//   to scratch, reloading 1.24GB/run. Design under 128 instead:
//     - 7 of 8 sample descriptors (28 B/px) live in LDS: 70 KB/block,
//       140 KB/CU at 2 blocks/CU (<=160). k-major layout => consecutive
//       lanes read consecutive uint2 => 2 lanes/bank = free (m136).
//     - registers pin only 7 words/px (pk7, ak quad, cf, ff) = 70 VGPRs
//       at PXT=10; + ~50 transient ~= 120 < 128 => fits the allocator's
//       own budget, no spill needed.
//   LDS filled once from px-major global arrays (coalesced uint4), then
//   descriptors never touch global memory again. Per-step traffic drops
//   79MB -> ~10-15MB (state gathers + 4.9MB write).
// Software grid barrier (HW-validated R8-R11): monotonic device-scope
// counter, target NBLK*t, threadfence release/acquire for XCD L2 coherence.
// Guard: occupancy-only (LDS+VGPR accounted by the occupancy API).

#define HH 480
#define WW 640
#define BB 4
#define HWSZ (HH * WW)        // 307200
#define NPIX (BB * HWSZ)      // 1228800
#define PROP_T 18
#define SLACK 704             // slack floats each side of state buffers
#define NTHR 256
#define PXT 10
#define NBLK (NPIX / (NTHR * PXT))   // 480

// Opaque-in-VGPR pin (prevents load re-materialization inside the t-loop).
#define TOUCH1(v)  asm volatile("" : "+v"(v))
#define TOUCH4(v)  do { TOUCH1((v).x); TOUCH1((v).y); TOUCH1((v).z); TOUCH1((v).w); } while (0)

struct f2u { float x, y; };   // 4-aligned pair load

__device__ __forceinline__ float fast_tanh(float x) {
    x = fminf(fmaxf(x, -15.0f), 15.0f);
    float e = __expf(2.0f * x);
    return __fdividef(e - 1.0f, e + 1.0f);
}

// Normalized affinities t[0..7] and aref (channel stride HWSZ).
__device__ __forceinline__ float affinities(const float* gb, float inv_scale,
                                            float t[8]) {
    float ssum = 1e-4f;
#pragma unroll
    for (int j = 0; j < 8; ++j) {
        float v = fast_tanh(gb[(16 + j) * HWSZ]) * inv_scale;
        t[j] = v; ssum += fabsf(v);
    }
    ssum = fmaxf(ssum, 1.0f);
    float rs = __fdividef(1.0f, ssum);
    float asum = 0.0f;
#pragma unroll
    for (int j = 0; j < 8; ++j) { t[j] *= rs; asum += t[j]; }
    return 1.0f - asum;
}

// Compact descriptor for sample k (k != 4) at pixel (y,x):
// pk = {rel i16 | wy u8 | wx u8}, akh = fp16(ak); boundary validity folded
// into (ak, wy, wx) exactly (R4-hardware-validated transform).
__device__ __forceinline__ void make_desc(int y, int x, int k,
                                          float dy, float dx, float ak,
                                          unsigned& pk, unsigned short& akh) {
    float py = (float)(y + k / 3 - 1) + dy;
    float px = (float)(x + k % 3 - 1) + dx;
    float y0f = floorf(py), x0f = floorf(px);
    float wy = py - y0f, wx = px - x0f;
    int y0 = (int)y0f, x0 = (int)x0f;
    if (y0 == -1)                 { ak *= wy;        wy = 1.0f; }
    else if (y0 == HH - 1)        { ak *= 1.0f - wy; wy = 0.0f; }
    else if (y0 < -1 || y0 >= HH) { ak = 0.0f; }
    if (x0 == -1)                 { ak *= wx;        wx = 1.0f; }
    else if (x0 == WW - 1)        { ak *= 1.0f - wx; wx = 0.0f; }
    else if (x0 < -1 || x0 >= WW) { ak = 0.0f; }
    int rel;
    if (ak == 0.0f) {
        rel = 0; wy = 0.0f; wx = 0.0f;
    } else {
        int yc = min(max(y0, -1), HH - 1);
        int xc = min(max(x0, -1), WW - 1);
        rel = (yc - y) * WW + (xc - x);          // |rel| <~ 1300 for N(0,1) offsets
        rel = min(max(rel, -32767), 32767);      // i16 safety (unreachable)
    }
    unsigned uy = (unsigned)(int)(wy * 255.0f + 0.5f);
    unsigned ux = (unsigned)(int)(wx * 255.0f + 0.5f);
    pk  = ((unsigned)(unsigned short)(short)rel << 16) | (uy << 8) | ux;
    akh = __half_as_ushort(__float2half(ak));
}

__device__ __forceinline__ float sample_rel(const float* __restrict__ fp,
                                            unsigned pk, unsigned short akh,
                                            float acc) {
    int rel = (int)(short)(pk >> 16);
    float wy = (float)((pk >> 8) & 0xffu) * (1.0f / 255.0f);
    float wx = (float)(pk & 0xffu) * (1.0f / 255.0f);
    float ak = __half2float(__ushort_as_half(akh));
    const float* p = fp + rel;
    f2u r0 = *reinterpret_cast<const f2u*>(p);
    f2u r1 = *reinterpret_cast<const f2u*>(p + WW);
    float bot = ak * wy;
    float top = ak - bot;
    float omwx = 1.0f - wx;
    acc = fmaf(top * omwx, r0.x, acc);
    acc = fmaf(top * wx,   r0.y, acc);
    acc = fmaf(bot * omwx, r1.x, acc);
    acc = fmaf(bot * wx,   r1.y, acc);
    return acc;
}

// Software grid barrier: monotonic counter, step-indexed target.
__device__ __forceinline__ void gsync(unsigned* __restrict__ bar,
                                      unsigned target) {
    __threadfence();          // release: make this block's writes visible
    __syncthreads();
    if (threadIdx.x == 0) {
        atomicAdd(bar, 1u);   // device-scope by default (m20)
        while (__hip_atomic_load(bar, __ATOMIC_ACQUIRE,
                                 __HIP_MEMORY_SCOPE_AGENT) < target) {
            __builtin_amdgcn_s_sleep(2);
        }
    }
    __syncthreads();
    __threadfence();          // acquire
}

// ---------------- one-time descriptor build (feeds both paths) ----------------
__global__ __launch_bounds__(NTHR) void precompute_kernel(
    const float* __restrict__ feat_init,
    const float* __restrict__ guid,
    const float* __restrict__ confidence,
    const float* __restrict__ feat_fix,
    const float* __restrict__ aff_scale,
    float* __restrict__ g0,               // state init (interior base of bufA)
    unsigned* __restrict__ pk1Arr,        // [NPIX][8] px-major
    unsigned short* __restrict__ akArr,   // [NPIX][8] px-major
    uint2* __restrict__ cffpArr) {        // {.x = aref fp16<<16|conf fp16, .y = bits(m*ff)}
    const int pix = blockIdx.x * NTHR + threadIdx.x;
    const int b = pix / HWSZ;
    const int q = pix - b * HWSZ;
    const int y = q / WW;
    const int x = q - y * WW;
    const float* gb = guid + (size_t)b * 24 * HWSZ + q;

    float ff = feat_fix[pix];
    float m  = (ff > 0.0f) ? 1.0f : 0.0f;
    float km = 1.0f - m;
    float conf = km * confidence[pix] + m;
    float f0   = km * feat_init[pix] + m * ff;
    g0[pix] = f0 * conf;

    const float inv_scale = __fdividef(1.0f, aff_scale[0] + 1e-8f);
    float t[8];
    float aref = affinities(gb, inv_scale, t);
    unsigned cf = ((unsigned)__half_as_ushort(__float2half(aref)) << 16)
                | (unsigned)__half_as_ushort(__float2half(conf));
    cffpArr[pix] = make_uint2(cf, __float_as_uint(m * ff));

    unsigned pk[8];
    unsigned short akh[8];
#pragma unroll
    for (int n = 0; n < 8; ++n) {
        const int k = (n < 4) ? n : (n + 1);
        float dy = gb[(2 * n) * HWSZ];
        float dx = gb[(2 * n + 1) * HWSZ];
        make_desc(y, x, k, dy, dx, t[n], pk[n], akh[n]);
    }
    uint4* pd = reinterpret_cast<uint4*>(pk1Arr) + 2 * pix;
    pd[0] = make_uint4(pk[0], pk[1], pk[2], pk[3]);
    pd[1] = make_uint4(pk[4], pk[5], pk[6], pk[7]);
    uint4 kv;
    kv.x = (unsigned)akh[0] | ((unsigned)akh[1] << 16);
    kv.y = (unsigned)akh[2] | ((unsigned)akh[3] << 16);
    kv.z = (unsigned)akh[4] | ((unsigned)akh[5] << 16);
    kv.w = (unsigned)akh[6] | ((unsigned)akh[7] << 16);
    reinterpret_cast<uint4*>(akArr)[pix] = kv;
}

// ---------------- persistent kernel: LDS descriptors + 70 pinned VGPRs ------
// 2 blocks/CU (LDS-limited: 70 KB x 2 = 140 <= 160 KB), 480 blocks on 256
// CUs. Per px: pk0..6 in LDS (k-major, conflict-free), pk7+ak+cf+ff in regs.
__global__ __launch_bounds__(NTHR) void persist_kernel(
    const unsigned* __restrict__ pk1Arr,
    const unsigned short* __restrict__ akArr,
    const uint2* __restrict__ cffpArr,
    float* __restrict__ fA,
    float* __restrict__ fB,
    float* __restrict__ out,
    unsigned* __restrict__ bar)
{
    __shared__ uint2    lds_p01[NTHR * PXT];   // pk0,pk1   20480 B
    __shared__ uint2    lds_p23[NTHR * PXT];   // pk2,pk3   20480 B
    __shared__ uint2    lds_p45[NTHR * PXT];   // pk4,pk5   20480 B
    __shared__ unsigned lds_p6 [NTHR * PXT];   // pk6       10240 B  => 71680 B

    const int base = blockIdx.x * (NTHR * PXT) + threadIdx.x;

    unsigned pk7r[PXT];                   // 1 reg/px
    uint4    akv[PXT];                    // 4 regs/px
    unsigned cfx[PXT];                    // 1 reg/px: {aref fp16 | conf fp16}
    float    ffv[PXT];                    // 1 reg/px: m*feat_fix

#pragma unroll
    for (int i = 0; i < PXT; ++i) {
        const int pix = base + i * NTHR;
        const int loc = i * NTHR + threadIdx.x;
        const uint4* pd = reinterpret_cast<const uint4*>(pk1Arr) + 2 * pix;
        uint4 A = pd[0], Bv = pd[1];
        lds_p01[loc] = make_uint2(A.x, A.y);
        lds_p23[loc] = make_uint2(A.z, A.w);
        lds_p45[loc] = make_uint2(Bv.x, Bv.y);
        lds_p6 [loc] = Bv.z;
        pk7r[i] = Bv.w;
        akv[i]  = reinterpret_cast<const uint4*>(akArr)[pix];
        uint2 cw = cffpArr[pix];
        cfx[i] = cw.x;
        ffv[i] = __uint_as_float(cw.y);
    }
    // Pin the register-resident set (opaque => no re-load inside t-loop).
#pragma unroll
    for (int i = 0; i < PXT; ++i) {
        TOUCH1(pk7r[i]); TOUCH4(akv[i]); TOUCH1(cfx[i]); TOUCH1(ffv[i]);
    }
    __syncthreads();

#pragma unroll 1
    for (int t = 0; t < PROP_T; ++t) {
        if (t) gsync(bar, (unsigned)NBLK * (unsigned)t);
        const float* fin = (t & 1) ? fB : fA;
        float* fout = (t == PROP_T - 1) ? out : ((t & 1) ? fA : fB);
        const bool last = (t == PROP_T - 1);
#pragma unroll
        for (int i = 0; i < PXT; ++i) {
            const int pix = base + i * NTHR;
            const int loc = i * NTHR + threadIdx.x;
            const float* fp = fin + pix;
            uint2 q01 = lds_p01[loc];
            uint2 q23 = lds_p23[loc];
            uint2 q45 = lds_p45[loc];
            unsigned q6 = lds_p6[loc];
            float aref = __half2float(__ushort_as_half((unsigned short)(cfx[i] >> 16)));
            float conf = __half2float(__ushort_as_half((unsigned short)(cfx[i] & 0xffffu)));
            float acc = aref * fp[0];
            uint4 K = akv[i];
            acc = sample_rel(fp, q01.x,   (unsigned short)(K.x & 0xffffu), acc);
            acc = sample_rel(fp, q01.y,   (unsigned short)(K.x >> 16),     acc);
            acc = sample_rel(fp, q23.x,   (unsigned short)(K.y & 0xffffu), acc);
            acc = sample_rel(fp, q23.y,   (unsigned short)(K.y >> 16),     acc);
            acc = sample_rel(fp, q45.x,   (unsigned short)(K.z & 0xffffu), acc);
            acc = sample_rel(fp, q45.y,   (unsigned short)(K.z >> 16),     acc);
            acc = sample_rel(fp, q6,      (unsigned short)(K.w & 0xffffu), acc);
            acc = sample_rel(fp, pk7r[i], (unsigned short)(K.w >> 16),     acc);
            float km = (ffv[i] > 0.0f) ? 0.0f : 1.0f;
            float fnew = fmaf(km, acc, ffv[i]);     // f' = km*prop + m*ff
            fout[pix] = last ? fnew : conf * fnew;  // g' = f'*conf
        }
    }
}

// ---------------- non-persistent fallback (compact streamed) ----------------
__global__ __launch_bounds__(NTHR) void step_kernel(
    const float* __restrict__ fin,
    float* __restrict__ fout,
    const unsigned* __restrict__ pk1Arr,
    const unsigned short* __restrict__ akArr,
    const uint2* __restrict__ cffpArr,
    int last) {
    const int pix = blockIdx.x * NTHR + threadIdx.x;
    const float* fp = fin + pix;
    const uint4* pd = reinterpret_cast<const uint4*>(pk1Arr) + 2 * pix;
    uint4 A = pd[0], B = pd[1];
    uint4 K = reinterpret_cast<const uint4*>(akArr)[pix];
    uint2 cw = cffpArr[pix];
    float ffv = __uint_as_float(cw.y);
    float aref = __half2float(__ushort_as_half((unsigned short)(cw.x >> 16)));
    float conf = __half2float(__ushort_as_half((unsigned short)(cw.x & 0xffffu)));
    float acc = aref * fp[0];
    acc = sample_rel(fp, A.x, (unsigned short)(K.x & 0xffffu), acc);
    acc = sample_rel(fp, A.y, (unsigned short)(K.x >> 16),     acc);
    acc = sample_rel(fp, A.z, (unsigned short)(K.y & 0xffffu), acc);
    acc = sample_rel(fp, A.w, (unsigned short)(K.y >> 16),     acc);
    acc = sample_rel(fp, B.x, (unsigned short)(K.z & 0xffffu), acc);
    acc = sample_rel(fp, B.y, (unsigned short)(K.z >> 16),     acc);
    acc = sample_rel(fp, B.z, (unsigned short)(K.w & 0xffffu), acc);
    acc = sample_rel(fp, B.w, (unsigned short)(K.w >> 16),     acc);
    float km = (ffv > 0.0f) ? 0.0f : 1.0f;
    float fnew = fmaf(km, acc, ffv);
    fout[pix] = last ? fnew : conf * fnew;
}

extern "C" void kernel_launch(void* const* d_in, const int* in_sizes, int n_in,
                              void* d_out, int out_size, void* d_ws, size_t ws_size,
                              hipStream_t stream) {
    const float* feat_init  = (const float*)d_in[0];
    const float* guidance   = (const float*)d_in[1];
    const float* confidence = (const float*)d_in[2];
    const float* feat_fix   = (const float*)d_in[3];
    const float* aff_scale  = (const float*)d_in[4];

    // ws layout (16B-aligned): bufA | bufB | pk1 | ak | cffp | bar (~84 MB)
    const size_t bufFloats = (size_t)NPIX + 2 * SLACK;      // x4 bytes, 16B-divisible
    float* bufA = (float*)d_ws;
    float* bufB = bufA + bufFloats;
    unsigned* pk1Arr = (unsigned*)(bufB + bufFloats);        // NPIX*8 u32
    unsigned short* akArr = (unsigned short*)(pk1Arr + 8 * (size_t)NPIX);  // NPIX*8 u16
    uint2* cffpArr = (uint2*)(akArr + 8 * (size_t)NPIX);     // NPIX uint2
    unsigned* bar = (unsigned*)(cffpArr + NPIX);             // barrier counter (16B)
    float* fA = bufA + SLACK;
    float* fB = bufB + SLACK;
    float* outp = (float*)d_out;

    // zero the slack strips (interiors fully written before read) + barrier
    hipMemsetAsync(bufA, 0, SLACK * sizeof(float), stream);
    hipMemsetAsync(bufA + SLACK + NPIX, 0, SLACK * sizeof(float), stream);
    hipMemsetAsync(bufB, 0, SLACK * sizeof(float), stream);
    hipMemsetAsync(bufB + SLACK + NPIX, 0, SLACK * sizeof(float), stream);
    hipMemsetAsync(bar, 0, 16, stream);

    precompute_kernel<<<NPIX / NTHR, NTHR, 0, stream>>>(
        feat_init, guidance, confidence, feat_fix, aff_scale,
        fA, pk1Arr, akArr, cffpArr);

    // ---- primary: persistent kernel (software barrier) ----
    // Guard ONLY on co-residency (deadlock safety); the occupancy API
    // accounts both LDS (71680 B/block => 2 blocks/CU) and VGPRs.
    bool tryPersist = false;
    {
        int occ = 0;
        if (hipOccupancyMaxActiveBlocksPerMultiprocessor(
                &occ, reinterpret_cast<const void*>(persist_kernel), NTHR, 0)
                == hipSuccess) {
            int dev = 0, cu = 0;
            hipGetDevice(&dev);
            hipDeviceGetAttribute(&cu, hipDeviceAttributeMultiprocessorCount, dev);
            if ((long)occ * cu >= NBLK) tryPersist = true;
        }
    }
    if (tryPersist) {
        persist_kernel<<<NBLK, NTHR, 0, stream>>>(
            pk1Arr, akArr, cffpArr, fA, fB, outp, bar);
        return;
    }

    // ---- fallback: 18 compact-streamed launches ----
    for (int t = 0; t < PROP_T; ++t) {
        const float* fin = (t & 1) ? fB : fA;
        float* fout = (t == PROP_T - 1) ? outp : ((t & 1) ? fA : fB);
        step_kernel<<<NPIX / NTHR, NTHR, 0, stream>>>(
            fin, fout, pk1Arr, akArr, cffpArr, (t == PROP_T - 1) ? 1 : 0);
    }
}

// Round 8
// 654.874 us; speedup vs baseline: 1.0047x; 1.0047x over previous
//
#include <hip/hip_runtime.h>
#include <hip/hip_fp16.h>

// NLSPN deformable propagation, B=4, H=480, W=640, 18 steps.
// Round 13: double persistent-kernel occupancy (8 -> 16 waves/CU).
//   R12 result: descriptors-in-LDS WORKED (VGPR=120 no spill, FETCH
//   1.64GB -> 126MB, one-time fetch) but timed stayed ~590us == fallback.
//   Counters say why: warm-path bottleneck is the bilinear gather latency
//   (17 dependent 8B loads/px/step from L2/L3), and persist ran at only
//   23% occupancy (LDS 71680B x 2 blocks = 143KB caps 2 blocks/CU = 8
//   waves/CU) -- 1/4 the fallback's latency hiding. Persist matched
//   fallback time with 1/8 the traffic => purely concurrency-starved.
//   Fix: PXT 10 -> 5. Descriptor LDS 35840B/block => 4 blocks/CU (140KB),
//   pinned regs 35 + ~50 transient < 128 => 16 waves/CU; NBLK=960 <= 1024
//   co-resident slots. Latency-bound time ~ 1/occupancy => ~2x faster.
// Software grid barrier (HW-validated R8-R12): monotonic device-scope
// counter, target NBLK*t, threadfence release/acquire for XCD L2 coherence.
// Guard: occupancy-only (LDS+VGPR accounted by the occupancy API).

#define HH 480
#define WW 640
#define BB 4
#define HWSZ (HH * WW)        // 307200
#define NPIX (BB * HWSZ)      // 1228800
#define PROP_T 18
#define SLACK 704             // slack floats each side of state buffers
#define NTHR 256
#define PXT 5
#define NBLK (NPIX / (NTHR * PXT))   // 960

// Opaque-in-VGPR pin (prevents load re-materialization inside the t-loop).
#define TOUCH1(v)  asm volatile("" : "+v"(v))
#define TOUCH4(v)  do { TOUCH1((v).x); TOUCH1((v).y); TOUCH1((v).z); TOUCH1((v).w); } while (0)

struct f2u { float x, y; };   // 4-aligned pair load

__device__ __forceinline__ float fast_tanh(float x) {
    x = fminf(fmaxf(x, -15.0f), 15.0f);
    float e = __expf(2.0f * x);
    return __fdividef(e - 1.0f, e + 1.0f);
}

// Normalized affinities t[0..7] and aref (channel stride HWSZ).
__device__ __forceinline__ float affinities(const float* gb, float inv_scale,
                                            float t[8]) {
    float ssum = 1e-4f;
#pragma unroll
    for (int j = 0; j < 8; ++j) {
        float v = fast_tanh(gb[(16 + j) * HWSZ]) * inv_scale;
        t[j] = v; ssum += fabsf(v);
    }
    ssum = fmaxf(ssum, 1.0f);
    float rs = __fdividef(1.0f, ssum);
    float asum = 0.0f;
#pragma unroll
    for (int j = 0; j < 8; ++j) { t[j] *= rs; asum += t[j]; }
    return 1.0f - asum;
}

// Compact descriptor for sample k (k != 4) at pixel (y,x):
// pk = {rel i16 | wy u8 | wx u8}, akh = fp16(ak); boundary validity folded
// into (ak, wy, wx) exactly (R4-hardware-validated transform).
__device__ __forceinline__ void make_desc(int y, int x, int k,
                                          float dy, float dx, float ak,
                                          unsigned& pk, unsigned short& akh) {
    float py = (float)(y + k / 3 - 1) + dy;
    float px = (float)(x + k % 3 - 1) + dx;
    float y0f = floorf(py), x0f = floorf(px);
    float wy = py - y0f, wx = px - x0f;
    int y0 = (int)y0f, x0 = (int)x0f;
    if (y0 == -1)                 { ak *= wy;        wy = 1.0f; }
    else if (y0 == HH - 1)        { ak *= 1.0f - wy; wy = 0.0f; }
    else if (y0 < -1 || y0 >= HH) { ak = 0.0f; }
    if (x0 == -1)                 { ak *= wx;        wx = 1.0f; }
    else if (x0 == WW - 1)        { ak *= 1.0f - wx; wx = 0.0f; }
    else if (x0 < -1 || x0 >= WW) { ak = 0.0f; }
    int rel;
    if (ak == 0.0f) {
        rel = 0; wy = 0.0f; wx = 0.0f;
    } else {
        int yc = min(max(y0, -1), HH - 1);
        int xc = min(max(x0, -1), WW - 1);
        rel = (yc - y) * WW + (xc - x);          // |rel| <~ 1300 for N(0,1) offsets
        rel = min(max(rel, -32767), 32767);      // i16 safety (unreachable)
    }
    unsigned uy = (unsigned)(int)(wy * 255.0f + 0.5f);
    unsigned ux = (unsigned)(int)(wx * 255.0f + 0.5f);
    pk  = ((unsigned)(unsigned short)(short)rel << 16) | (uy << 8) | ux;
    akh = __half_as_ushort(__float2half(ak));
}

__device__ __forceinline__ float sample_rel(const float* __restrict__ fp,
                                            unsigned pk, unsigned short akh,
                                            float acc) {
    int rel = (int)(short)(pk >> 16);
    float wy = (float)((pk >> 8) & 0xffu) * (1.0f / 255.0f);
    float wx = (float)(pk & 0xffu) * (1.0f / 255.0f);
    float ak = __half2float(__ushort_as_half(akh));
    const float* p = fp + rel;
    f2u r0 = *reinterpret_cast<const f2u*>(p);
    f2u r1 = *reinterpret_cast<const f2u*>(p + WW);
    float bot = ak * wy;
    float top = ak - bot;
    float omwx = 1.0f - wx;
    acc = fmaf(top * omwx, r0.x, acc);
    acc = fmaf(top * wx,   r0.y, acc);
    acc = fmaf(bot * omwx, r1.x, acc);
    acc = fmaf(bot * wx,   r1.y, acc);
    return acc;
}

// Software grid barrier: monotonic counter, step-indexed target.
__device__ __forceinline__ void gsync(unsigned* __restrict__ bar,
                                      unsigned target) {
    __threadfence();          // release: make this block's writes visible
    __syncthreads();
    if (threadIdx.x == 0) {
        atomicAdd(bar, 1u);   // device-scope by default (m20)
        while (__hip_atomic_load(bar, __ATOMIC_ACQUIRE,
                                 __HIP_MEMORY_SCOPE_AGENT) < target) {
            __builtin_amdgcn_s_sleep(2);
        }
    }
    __syncthreads();
    __threadfence();          // acquire
}

// ---------------- one-time descriptor build (feeds both paths) ----------------
__global__ __launch_bounds__(NTHR) void precompute_kernel(
    const float* __restrict__ feat_init,
    const float* __restrict__ guid,
    const float* __restrict__ confidence,
    const float* __restrict__ feat_fix,
    const float* __restrict__ aff_scale,
    float* __restrict__ g0,               // state init (interior base of bufA)
    unsigned* __restrict__ pk1Arr,        // [NPIX][8] px-major
    unsigned short* __restrict__ akArr,   // [NPIX][8] px-major
    uint2* __restrict__ cffpArr) {        // {.x = aref fp16<<16|conf fp16, .y = bits(m*ff)}
    const int pix = blockIdx.x * NTHR + threadIdx.x;
    const int b = pix / HWSZ;
    const int q = pix - b * HWSZ;
    const int y = q / WW;
    const int x = q - y * WW;
    const float* gb = guid + (size_t)b * 24 * HWSZ + q;

    float ff = feat_fix[pix];
    float m  = (ff > 0.0f) ? 1.0f : 0.0f;
    float km = 1.0f - m;
    float conf = km * confidence[pix] + m;
    float f0   = km * feat_init[pix] + m * ff;
    g0[pix] = f0 * conf;

    const float inv_scale = __fdividef(1.0f, aff_scale[0] + 1e-8f);
    float t[8];
    float aref = affinities(gb, inv_scale, t);
    unsigned cf = ((unsigned)__half_as_ushort(__float2half(aref)) << 16)
                | (unsigned)__half_as_ushort(__float2half(conf));
    cffpArr[pix] = make_uint2(cf, __float_as_uint(m * ff));

    unsigned pk[8];
    unsigned short akh[8];
#pragma unroll
    for (int n = 0; n < 8; ++n) {
        const int k = (n < 4) ? n : (n + 1);
        float dy = gb[(2 * n) * HWSZ];
        float dx = gb[(2 * n + 1) * HWSZ];
        make_desc(y, x, k, dy, dx, t[n], pk[n], akh[n]);
    }
    uint4* pd = reinterpret_cast<uint4*>(pk1Arr) + 2 * pix;
    pd[0] = make_uint4(pk[0], pk[1], pk[2], pk[3]);
    pd[1] = make_uint4(pk[4], pk[5], pk[6], pk[7]);
    uint4 kv;
    kv.x = (unsigned)akh[0] | ((unsigned)akh[1] << 16);
    kv.y = (unsigned)akh[2] | ((unsigned)akh[3] << 16);
    kv.z = (unsigned)akh[4] | ((unsigned)akh[5] << 16);
    kv.w = (unsigned)akh[6] | ((unsigned)akh[7] << 16);
    reinterpret_cast<uint4*>(akArr)[pix] = kv;
}

// ---------------- persistent kernel: LDS descriptors, 4 blocks/CU ----------
// PXT=5: descriptor LDS 35840 B/block => 4 blocks/CU (140 KB of 160), 16
// waves/CU. Pinned regs: pk7(5)+ak(20)+cf(5)+ff(5)=35, + ~50 transient < 128.
// 960 blocks <= 1024 co-resident slots.
__global__ __launch_bounds__(NTHR) void persist_kernel(
    const unsigned* __restrict__ pk1Arr,
    const unsigned short* __restrict__ akArr,
    const uint2* __restrict__ cffpArr,
    float* __restrict__ fA,
    float* __restrict__ fB,
    float* __restrict__ out,
    unsigned* __restrict__ bar)
{
    __shared__ uint2    lds_p01[NTHR * PXT];   // pk0,pk1   10240 B
    __shared__ uint2    lds_p23[NTHR * PXT];   // pk2,pk3   10240 B
    __shared__ uint2    lds_p45[NTHR * PXT];   // pk4,pk5   10240 B
    __shared__ unsigned lds_p6 [NTHR * PXT];   // pk6        5120 B  => 35840 B

    const int base = blockIdx.x * (NTHR * PXT) + threadIdx.x;

    unsigned pk7r[PXT];                   // 1 reg/px
    uint4    akv[PXT];                    // 4 regs/px
    unsigned cfx[PXT];                    // 1 reg/px: {aref fp16 | conf fp16}
    float    ffv[PXT];                    // 1 reg/px: m*feat_fix

#pragma unroll
    for (int i = 0; i < PXT; ++i) {
        const int pix = base + i * NTHR;
        const int loc = i * NTHR + threadIdx.x;
        const uint4* pd = reinterpret_cast<const uint4*>(pk1Arr) + 2 * pix;
        uint4 A = pd[0], Bv = pd[1];
        lds_p01[loc] = make_uint2(A.x, A.y);
        lds_p23[loc] = make_uint2(A.z, A.w);
        lds_p45[loc] = make_uint2(Bv.x, Bv.y);
        lds_p6 [loc] = Bv.z;
        pk7r[i] = Bv.w;
        akv[i]  = reinterpret_cast<const uint4*>(akArr)[pix];
        uint2 cw = cffpArr[pix];
        cfx[i] = cw.x;
        ffv[i] = __uint_as_float(cw.y);
    }
    // Pin the register-resident set (opaque => no re-load inside t-loop).
#pragma unroll
    for (int i = 0; i < PXT; ++i) {
        TOUCH1(pk7r[i]); TOUCH4(akv[i]); TOUCH1(cfx[i]); TOUCH1(ffv[i]);
    }
    __syncthreads();

#pragma unroll 1
    for (int t = 0; t < PROP_T; ++t) {
        if (t) gsync(bar, (unsigned)NBLK * (unsigned)t);
        const float* fin = (t & 1) ? fB : fA;
        float* fout = (t == PROP_T - 1) ? out : ((t & 1) ? fA : fB);
        const bool last = (t == PROP_T - 1);
#pragma unroll
        for (int i = 0; i < PXT; ++i) {
            const int pix = base + i * NTHR;
            const int loc = i * NTHR + threadIdx.x;
            const float* fp = fin + pix;
            uint2 q01 = lds_p01[loc];
            uint2 q23 = lds_p23[loc];
            uint2 q45 = lds_p45[loc];
            unsigned q6 = lds_p6[loc];
            float aref = __half2float(__ushort_as_half((unsigned short)(cfx[i] >> 16)));
            float conf = __half2float(__ushort_as_half((unsigned short)(cfx[i] & 0xffffu)));
            float acc = aref * fp[0];
            uint4 K = akv[i];
            acc = sample_rel(fp, q01.x,   (unsigned short)(K.x & 0xffffu), acc);
            acc = sample_rel(fp, q01.y,   (unsigned short)(K.x >> 16),     acc);
            acc = sample_rel(fp, q23.x,   (unsigned short)(K.y & 0xffffu), acc);
            acc = sample_rel(fp, q23.y,   (unsigned short)(K.y >> 16),     acc);
            acc = sample_rel(fp, q45.x,   (unsigned short)(K.z & 0xffffu), acc);
            acc = sample_rel(fp, q45.y,   (unsigned short)(K.z >> 16),     acc);
            acc = sample_rel(fp, q6,      (unsigned short)(K.w & 0xffffu), acc);
            acc = sample_rel(fp, pk7r[i], (unsigned short)(K.w >> 16),     acc);
            float km = (ffv[i] > 0.0f) ? 0.0f : 1.0f;
            float fnew = fmaf(km, acc, ffv[i]);     // f' = km*prop + m*ff
            fout[pix] = last ? fnew : conf * fnew;  // g' = f'*conf
        }
    }
}

// ---------------- non-persistent fallback (compact streamed) ----------------
__global__ __launch_bounds__(NTHR) void step_kernel(
    const float* __restrict__ fin,
    float* __restrict__ fout,
    const unsigned* __restrict__ pk1Arr,
    const unsigned short* __restrict__ akArr,
    const uint2* __restrict__ cffpArr,
    int last) {
    const int pix = blockIdx.x * NTHR + threadIdx.x;
    const float* fp = fin + pix;
    const uint4* pd = reinterpret_cast<const uint4*>(pk1Arr) + 2 * pix;
    uint4 A = pd[0], B = pd[1];
    uint4 K = reinterpret_cast<const uint4*>(akArr)[pix];
    uint2 cw = cffpArr[pix];
    float ffv = __uint_as_float(cw.y);
    float aref = __half2float(__ushort_as_half((unsigned short)(cw.x >> 16)));
    float conf = __half2float(__ushort_as_half((unsigned short)(cw.x & 0xffffu)));
    float acc = aref * fp[0];
    acc = sample_rel(fp, A.x, (unsigned short)(K.x & 0xffffu), acc);
    acc = sample_rel(fp, A.y, (unsigned short)(K.x >> 16),     acc);
    acc = sample_rel(fp, A.z, (unsigned short)(K.y & 0xffffu), acc);
    acc = sample_rel(fp, A.w, (unsigned short)(K.y >> 16),     acc);
    acc = sample_rel(fp, B.x, (unsigned short)(K.z & 0xffffu), acc);
    acc = sample_rel(fp, B.y, (unsigned short)(K.z >> 16),     acc);
    acc = sample_rel(fp, B.z, (unsigned short)(K.w & 0xffffu), acc);
    acc = sample_rel(fp, B.w, (unsigned short)(K.w >> 16),     acc);
    float km = (ffv > 0.0f) ? 0.0f : 1.0f;
    float fnew = fmaf(km, acc, ffv);
    fout[pix] = last ? fnew : conf * fnew;
}

extern "C" void kernel_launch(void* const* d_in, const int* in_sizes, int n_in,
                              void* d_out, int out_size, void* d_ws, size_t ws_size,
                              hipStream_t stream) {
    const float* feat_init  = (const float*)d_in[0];
    const float* guidance   = (const float*)d_in[1];
    const float* confidence = (const float*)d_in[2];
    const float* feat_fix   = (const float*)d_in[3];
    const float* aff_scale  = (const float*)d_in[4];

    // ws layout (16B-aligned): bufA | bufB | pk1 | ak | cffp | bar (~84 MB)
    const size_t bufFloats = (size_t)NPIX + 2 * SLACK;      // x4 bytes, 16B-divisible
    float* bufA = (float*)d_ws;
    float* bufB = bufA + bufFloats;
    unsigned* pk1Arr = (unsigned*)(bufB + bufFloats);        // NPIX*8 u32
    unsigned short* akArr = (unsigned short*)(pk1Arr + 8 * (size_t)NPIX);  // NPIX*8 u16
    uint2* cffpArr = (uint2*)(akArr + 8 * (size_t)NPIX);     // NPIX uint2
    unsigned* bar = (unsigned*)(cffpArr + NPIX);             // barrier counter (16B)
    float* fA = bufA + SLACK;
    float* fB = bufB + SLACK;
    float* outp = (float*)d_out;

    // zero the slack strips (interiors fully written before read) + barrier
    hipMemsetAsync(bufA, 0, SLACK * sizeof(float), stream);
    hipMemsetAsync(bufA + SLACK + NPIX, 0, SLACK * sizeof(float), stream);
    hipMemsetAsync(bufB, 0, SLACK * sizeof(float), stream);
    hipMemsetAsync(bufB + SLACK + NPIX, 0, SLACK * sizeof(float), stream);
    hipMemsetAsync(bar, 0, 16, stream);

    precompute_kernel<<<NPIX / NTHR, NTHR, 0, stream>>>(
        feat_init, guidance, confidence, feat_fix, aff_scale,
        fA, pk1Arr, akArr, cffpArr);

    // ---- primary: persistent kernel (software barrier) ----
    // Guard ONLY on co-residency (deadlock safety); the occupancy API
    // accounts both LDS (35840 B/block => 4 blocks/CU) and VGPRs.
    bool tryPersist = false;
    {
        int occ = 0;
        if (hipOccupancyMaxActiveBlocksPerMultiprocessor(
                &occ, reinterpret_cast<const void*>(persist_kernel), NTHR, 0)
                == hipSuccess) {
            int dev = 0, cu = 0;
            hipGetDevice(&dev);
            hipDeviceGetAttribute(&cu, hipDeviceAttributeMultiprocessorCount, dev);
            if ((long)occ * cu >= NBLK) tryPersist = true;
        }
    }
    if (tryPersist) {
        persist_kernel<<<NBLK, NTHR, 0, stream>>>(
            pk1Arr, akArr, cffpArr, fA, fB, outp, bar);
        return;
    }

    // ---- fallback: 18 compact-streamed launches ----
    for (int t = 0; t < PROP_T; ++t) {
        const float* fin = (t & 1) ? fB : fA;
        float* fout = (t == PROP_T - 1) ? outp : ((t & 1) ? fA : fB);
        step_kernel<<<NPIX / NTHR, NTHR, 0, stream>>>(
            fin, fout, pk1Arr, akArr, cffpArr, (t == PROP_T - 1) ? 1 : 0);
    }
}

// Round 10
// 653.569 us; speedup vs baseline: 1.0067x; 1.0020x over previous
//
#include <hip/hip_runtime.h>
#include <hip/hip_fp16.h>

// NLSPN deformable propagation, B=4, H=480, W=640, 18 steps.
// Round 15: resubmit R14 (container infra failure, no kernel verdict).
//   Audit found no fault/hang hazard: tile staging and outlier taps stay
//   inside SLACK strips; gsync protocol is the R12/R13 HW-validated one;
//   occupancy guard routes to fallback if co-residency isn't guaranteed.
// R14 theory (unchanged): R12 (8 w/CU), R13 (16 w/CU) and fallback
//   (32 w/CU) all run 32.5 us/step => bottleneck is the per-CU scattered
//   vector-memory request rate (17 divergent 8B gathers/px), not latency.
//   Fix: per step each block stages a 14-row window (8960 floats, 35840 B
//   LDS, coalesced float4) and the 17 taps become LDS reads; rare
//   out-of-window samples use a guarded global fallback (identical math).
//   Descriptors in REGISTERS at PXT=5 (70 pinned + TOUCH; fits <128).
//   LDS = tile only => 4 blocks/CU, 16 waves/CU, NBLK=960 <= 1024 slots.
// Software grid barrier (HW-validated R8-R13): monotonic device-scope
// counter, target NBLK*t, threadfence release/acquire for XCD L2 coherence.

#define HH 480
#define WW 640
#define BB 4
#define HWSZ (HH * WW)        // 307200
#define NPIX (BB * HWSZ)      // 1228800
#define PROP_T 18
#define SLACK 4096            // slack floats each side of state buffers (>= halo 3840)
#define NTHR 256
#define PXT 5
#define NBLK (NPIX / (NTHR * PXT))   // 960

#define TILE_ROWS 14
#define TILE_F (TILE_ROWS * WW)      // 8960 floats = 35840 B
#define TILE_HALO (6 * WW)           // 3840 floats above block's first pixel
#define TILE_MAXOFF (TILE_F - WW - 2) // last valid r0 offset (needs off+WW+1)

// Opaque-in-VGPR pin (prevents load re-materialization inside the t-loop).
#define TOUCH1(v)  asm volatile("" : "+v"(v))
#define TOUCH4(v)  do { TOUCH1((v).x); TOUCH1((v).y); TOUCH1((v).z); TOUCH1((v).w); } while (0)

struct f2u { float x, y; };   // 4-aligned pair load (ds_read2_b32-friendly in LDS)

__device__ __forceinline__ float fast_tanh(float x) {
    x = fminf(fmaxf(x, -15.0f), 15.0f);
    float e = __expf(2.0f * x);
    return __fdividef(e - 1.0f, e + 1.0f);
}

// Normalized affinities t[0..7] and aref (channel stride HWSZ).
__device__ __forceinline__ float affinities(const float* gb, float inv_scale,
                                            float t[8]) {
    float ssum = 1e-4f;
#pragma unroll
    for (int j = 0; j < 8; ++j) {
        float v = fast_tanh(gb[(16 + j) * HWSZ]) * inv_scale;
        t[j] = v; ssum += fabsf(v);
    }
    ssum = fmaxf(ssum, 1.0f);
    float rs = __fdividef(1.0f, ssum);
    float asum = 0.0f;
#pragma unroll
    for (int j = 0; j < 8; ++j) { t[j] *= rs; asum += t[j]; }
    return 1.0f - asum;
}

// Compact descriptor for sample k (k != 4) at pixel (y,x):
// pk = {rel i16 | wy u8 | wx u8}, akh = fp16(ak); boundary validity folded
// into (ak, wy, wx) exactly (R4-hardware-validated transform).
__device__ __forceinline__ void make_desc(int y, int x, int k,
                                          float dy, float dx, float ak,
                                          unsigned& pk, unsigned short& akh) {
    float py = (float)(y + k / 3 - 1) + dy;
    float px = (float)(x + k % 3 - 1) + dx;
    float y0f = floorf(py), x0f = floorf(px);
    float wy = py - y0f, wx = px - x0f;
    int y0 = (int)y0f, x0 = (int)x0f;
    if (y0 == -1)                 { ak *= wy;        wy = 1.0f; }
    else if (y0 == HH - 1)        { ak *= 1.0f - wy; wy = 0.0f; }
    else if (y0 < -1 || y0 >= HH) { ak = 0.0f; }
    if (x0 == -1)                 { ak *= wx;        wx = 1.0f; }
    else if (x0 == WW - 1)        { ak *= 1.0f - wx; wx = 0.0f; }
    else if (x0 < -1 || x0 >= WW) { ak = 0.0f; }
    int rel;
    if (ak == 0.0f) {
        rel = 0; wy = 0.0f; wx = 0.0f;
    } else {
        int yc = min(max(y0, -1), HH - 1);
        int xc = min(max(x0, -1), WW - 1);
        rel = (yc - y) * WW + (xc - x);          // typically |rel| < ~4500
        rel = min(max(rel, -32767), 32767);      // i16 safety (unreachable)
    }
    unsigned uy = (unsigned)(int)(wy * 255.0f + 0.5f);
    unsigned ux = (unsigned)(int)(wx * 255.0f + 0.5f);
    pk  = ((unsigned)(unsigned short)(short)rel << 16) | (uy << 8) | ux;
    akh = __half_as_ushort(__float2half(ak));
}

// Global-memory bilinear tap (fallback kernel + out-of-tile outliers).
__device__ __forceinline__ float sample_rel(const float* __restrict__ fp,
                                            unsigned pk, unsigned short akh,
                                            float acc) {
    int rel = (int)(short)(pk >> 16);
    float wy = (float)((pk >> 8) & 0xffu) * (1.0f / 255.0f);
    float wx = (float)(pk & 0xffu) * (1.0f / 255.0f);
    float ak = __half2float(__ushort_as_half(akh));
    const float* p = fp + rel;
    f2u r0 = *reinterpret_cast<const f2u*>(p);
    f2u r1 = *reinterpret_cast<const f2u*>(p + WW);
    float bot = ak * wy;
    float top = ak - bot;
    float omwx = 1.0f - wx;
    acc = fmaf(top * omwx, r0.x, acc);
    acc = fmaf(top * wx,   r0.y, acc);
    acc = fmaf(bot * omwx, r1.x, acc);
    acc = fmaf(bot * wx,   r1.y, acc);
    return acc;
}

// LDS-tile bilinear tap with rare global fallback for out-of-window offsets.
__device__ __forceinline__ float sample_tile(const float* tile,
                                             const float* __restrict__ fp,
                                             int off_base,
                                             unsigned pk, unsigned short akh,
                                             float acc) {
    int rel = (int)(short)(pk >> 16);
    float wy = (float)((pk >> 8) & 0xffu) * (1.0f / 255.0f);
    float wx = (float)(pk & 0xffu) * (1.0f / 255.0f);
    float ak = __half2float(__ushort_as_half(akh));
    int off = off_base + rel;
    f2u r0, r1;
    if (off >= 0 && off <= TILE_MAXOFF) {          // common path: LDS
        r0 = *reinterpret_cast<const f2u*>(tile + off);
        r1 = *reinterpret_cast<const f2u*>(tile + off + WW);
    } else {                                       // rare outlier: global
        const float* p = fp + rel;
        r0 = *reinterpret_cast<const f2u*>(p);
        r1 = *reinterpret_cast<const f2u*>(p + WW);
    }
    float bot = ak * wy;
    float top = ak - bot;
    float omwx = 1.0f - wx;
    acc = fmaf(top * omwx, r0.x, acc);
    acc = fmaf(top * wx,   r0.y, acc);
    acc = fmaf(bot * omwx, r1.x, acc);
    acc = fmaf(bot * wx,   r1.y, acc);
    return acc;
}

// Software grid barrier: monotonic counter, step-indexed target.
__device__ __forceinline__ void gsync(unsigned* __restrict__ bar,
                                      unsigned target) {
    __threadfence();          // release: make this block's writes visible
    __syncthreads();
    if (threadIdx.x == 0) {
        atomicAdd(bar, 1u);   // device-scope by default (m20)
        while (__hip_atomic_load(bar, __ATOMIC_ACQUIRE,
                                 __HIP_MEMORY_SCOPE_AGENT) < target) {
            __builtin_amdgcn_s_sleep(2);
        }
    }
    __syncthreads();
    __threadfence();          // acquire
}

// ---------------- one-time descriptor build (feeds both paths) ----------------
__global__ __launch_bounds__(NTHR) void precompute_kernel(
    const float* __restrict__ feat_init,
    const float* __restrict__ guid,
    const float* __restrict__ confidence,
    const float* __restrict__ feat_fix,
    const float* __restrict__ aff_scale,
    float* __restrict__ g0,               // state init (interior base of bufA)
    unsigned* __restrict__ pk1Arr,        // [NPIX][8] px-major
    unsigned short* __restrict__ akArr,   // [NPIX][8] px-major
    uint2* __restrict__ cffpArr) {        // {.x = aref fp16<<16|conf fp16, .y = bits(m*ff)}
    const int pix = blockIdx.x * NTHR + threadIdx.x;
    const int b = pix / HWSZ;
    const int q = pix - b * HWSZ;
    const int y = q / WW;
    const int x = q - y * WW;
    const float* gb = guid + (size_t)b * 24 * HWSZ + q;

    float ff = feat_fix[pix];
    float m  = (ff > 0.0f) ? 1.0f : 0.0f;
    float km = 1.0f - m;
    float conf = km * confidence[pix] + m;
    float f0   = km * feat_init[pix] + m * ff;
    g0[pix] = f0 * conf;

    const float inv_scale = __fdividef(1.0f, aff_scale[0] + 1e-8f);
    float t[8];
    float aref = affinities(gb, inv_scale, t);
    unsigned cf = ((unsigned)__half_as_ushort(__float2half(aref)) << 16)
                | (unsigned)__half_as_ushort(__float2half(conf));
    cffpArr[pix] = make_uint2(cf, __float_as_uint(m * ff));

    unsigned pk[8];
    unsigned short akh[8];
#pragma unroll
    for (int n = 0; n < 8; ++n) {
        const int k = (n < 4) ? n : (n + 1);
        float dy = gb[(2 * n) * HWSZ];
        float dx = gb[(2 * n + 1) * HWSZ];
        make_desc(y, x, k, dy, dx, t[n], pk[n], akh[n]);
    }
    uint4* pd = reinterpret_cast<uint4*>(pk1Arr) + 2 * pix;
    pd[0] = make_uint4(pk[0], pk[1], pk[2], pk[3]);
    pd[1] = make_uint4(pk[4], pk[5], pk[6], pk[7]);
    uint4 kv;
    kv.x = (unsigned)akh[0] | ((unsigned)akh[1] << 16);
    kv.y = (unsigned)akh[2] | ((unsigned)akh[3] << 16);
    kv.z = (unsigned)akh[4] | ((unsigned)akh[5] << 16);
    kv.w = (unsigned)akh[6] | ((unsigned)akh[7] << 16);
    reinterpret_cast<uint4*>(akArr)[pix] = kv;
}

// ---------------- persistent kernel: LDS state tile + reg descriptors -------
// Block owns 1280 px = 2 rows. Tile = 14 rows (6 halo each side) = 35840 B
// LDS => 4 blocks/CU, 16 waves/CU. Descriptors: 14 regs/px x 5 px = 70
// pinned VGPRs (R12/R13-validated to fit under the 128 cap with TOUCH).
__global__ __launch_bounds__(NTHR) void persist_kernel(
    const unsigned* __restrict__ pk1Arr,
    const unsigned short* __restrict__ akArr,
    const uint2* __restrict__ cffpArr,
    float* __restrict__ fA,
    float* __restrict__ fB,
    float* __restrict__ out,
    unsigned* __restrict__ bar)
{
    __shared__ float tile[TILE_F];        // 35840 B

    const int tid = threadIdx.x;
    const int base = blockIdx.x * (NTHR * PXT);   // block's first pixel
    const int lo = base - TILE_HALO;              // tile's first global float

    uint4 pka[PXT], pkb[PXT], akv[PXT];   // 12 regs/px
    unsigned cfx[PXT];                    // 1 reg/px: {aref fp16 | conf fp16}
    float    ffv[PXT];                    // 1 reg/px: m*feat_fix

#pragma unroll
    for (int i = 0; i < PXT; ++i) {
        const int pix = base + i * NTHR + tid;
        const uint4* pd = reinterpret_cast<const uint4*>(pk1Arr) + 2 * pix;
        pka[i] = pd[0];
        pkb[i] = pd[1];
        akv[i] = reinterpret_cast<const uint4*>(akArr)[pix];
        uint2 cw = cffpArr[pix];
        cfx[i] = cw.x;
        ffv[i] = __uint_as_float(cw.y);
    }
    // Pin: opaque => no re-load inside the t-loop (R9 failure mode blocked).
#pragma unroll
    for (int i = 0; i < PXT; ++i) {
        TOUCH4(pka[i]); TOUCH4(pkb[i]); TOUCH4(akv[i]);
        TOUCH1(cfx[i]); TOUCH1(ffv[i]);
    }

#pragma unroll 1
    for (int t = 0; t < PROP_T; ++t) {
        if (t) gsync(bar, (unsigned)NBLK * (unsigned)t);
        const float* fin = (t & 1) ? fB : fA;
        float* fout = (t == PROP_T - 1) ? out : ((t & 1) ? fA : fB);
        const bool last = (t == PROP_T - 1);

        // Stage the 14-row window (coalesced float4; fin+lo is 16B-aligned).
        const float4* src = reinterpret_cast<const float4*>(fin + lo);
        float4* dst = reinterpret_cast<float4*>(tile);
#pragma unroll
        for (int j = 0; j < (TILE_F / 4 + NTHR - 1) / NTHR; ++j) {
            int idx = j * NTHR + tid;
            if (idx < TILE_F / 4) dst[idx] = src[idx];
        }
        __syncthreads();

#pragma unroll
        for (int i = 0; i < PXT; ++i) {
            const int pl = i * NTHR + tid;          // 0..1279 in block
            const int pix = base + pl;
            const int ob = pl + TILE_HALO;          // pixel's tile offset
            const float* fp = fin + pix;            // fallback base
            float aref = __half2float(__ushort_as_half((unsigned short)(cfx[i] >> 16)));
            float conf = __half2float(__ushort_as_half((unsigned short)(cfx[i] & 0xffffu)));
            float acc = aref * tile[ob];
            uint4 A = pka[i], B = pkb[i], K = akv[i];
            acc = sample_tile(tile, fp, ob, A.x, (unsigned short)(K.x & 0xffffu), acc);
            acc = sample_tile(tile, fp, ob, A.y, (unsigned short)(K.x >> 16),     acc);
            acc = sample_tile(tile, fp, ob, A.z, (unsigned short)(K.y & 0xffffu), acc);
            acc = sample_tile(tile, fp, ob, A.w, (unsigned short)(K.y >> 16),     acc);
            acc = sample_tile(tile, fp, ob, B.x, (unsigned short)(K.z & 0xffffu), acc);
            acc = sample_tile(tile, fp, ob, B.y, (unsigned short)(K.z >> 16),     acc);
            acc = sample_tile(tile, fp, ob, B.z, (unsigned short)(K.w & 0xffffu), acc);
            acc = sample_tile(tile, fp, ob, B.w, (unsigned short)(K.w >> 16),     acc);
            float km = (ffv[i] > 0.0f) ? 0.0f : 1.0f;
            float fnew = fmaf(km, acc, ffv[i]);     // f' = km*prop + m*ff
            fout[pix] = last ? fnew : conf * fnew;  // g' = f'*conf
        }
        // Next iteration's gsync (__syncthreads inside) guards tile reuse.
    }
}

// ---------------- non-persistent fallback (compact streamed) ----------------
__global__ __launch_bounds__(NTHR) void step_kernel(
    const float* __restrict__ fin,
    float* __restrict__ fout,
    const unsigned* __restrict__ pk1Arr,
    const unsigned short* __restrict__ akArr,
    const uint2* __restrict__ cffpArr,
    int last) {
    const int pix = blockIdx.x * NTHR + threadIdx.x;
    const float* fp = fin + pix;
    const uint4* pd = reinterpret_cast<const uint4*>(pk1Arr) + 2 * pix;
    uint4 A = pd[0], B = pd[1];
    uint4 K = reinterpret_cast<const uint4*>(akArr)[pix];
    uint2 cw = cffpArr[pix];
    float ffv = __uint_as_float(cw.y);
    float aref = __half2float(__ushort_as_half((unsigned short)(cw.x >> 16)));
    float conf = __half2float(__ushort_as_half((unsigned short)(cw.x & 0xffffu)));
    float acc = aref * fp[0];
    acc = sample_rel(fp, A.x, (unsigned short)(K.x & 0xffffu), acc);
    acc = sample_rel(fp, A.y, (unsigned short)(K.x >> 16),     acc);
    acc = sample_rel(fp, A.z, (unsigned short)(K.y & 0xffffu), acc);
    acc = sample_rel(fp, A.w, (unsigned short)(K.y >> 16),     acc);
    acc = sample_rel(fp, B.x, (unsigned short)(K.z & 0xffffu), acc);
    acc = sample_rel(fp, B.y, (unsigned short)(K.z >> 16),     acc);
    acc = sample_rel(fp, B.z, (unsigned short)(K.w & 0xffffu), acc);
    acc = sample_rel(fp, B.w, (unsigned short)(K.w >> 16),     acc);
    float km = (ffv > 0.0f) ? 0.0f : 1.0f;
    float fnew = fmaf(km, acc, ffv);
    fout[pix] = last ? fnew : conf * fnew;
}

extern "C" void kernel_launch(void* const* d_in, const int* in_sizes, int n_in,
                              void* d_out, int out_size, void* d_ws, size_t ws_size,
                              hipStream_t stream) {
    const float* feat_init  = (const float*)d_in[0];
    const float* guidance   = (const float*)d_in[1];
    const float* confidence = (const float*)d_in[2];
    const float* feat_fix   = (const float*)d_in[3];
    const float* aff_scale  = (const float*)d_in[4];

    // ws layout (16B-aligned): bufA | bufB | pk1 | ak | cffp | bar (~79 MB)
    const size_t bufFloats = (size_t)NPIX + 2 * SLACK;      // x4 bytes, 16B-divisible
    float* bufA = (float*)d_ws;
    float* bufB = bufA + bufFloats;
    unsigned* pk1Arr = (unsigned*)(bufB + bufFloats);        // NPIX*8 u32
    unsigned short* akArr = (unsigned short*)(pk1Arr + 8 * (size_t)NPIX);  // NPIX*8 u16
    uint2* cffpArr = (uint2*)(akArr + 8 * (size_t)NPIX);     // NPIX uint2
    unsigned* bar = (unsigned*)(cffpArr + NPIX);             // barrier counter (16B)
    float* fA = bufA + SLACK;
    float* fB = bufB + SLACK;
    float* outp = (float*)d_out;

    // zero the slack strips (tile halos / boundary taps read them) + barrier
    hipMemsetAsync(bufA, 0, SLACK * sizeof(float), stream);
    hipMemsetAsync(bufA + SLACK + NPIX, 0, SLACK * sizeof(float), stream);
    hipMemsetAsync(bufB, 0, SLACK * sizeof(float), stream);
    hipMemsetAsync(bufB + SLACK + NPIX, 0, SLACK * sizeof(float), stream);
    hipMemsetAsync(bar, 0, 16, stream);

    precompute_kernel<<<NPIX / NTHR, NTHR, 0, stream>>>(
        feat_init, guidance, confidence, feat_fix, aff_scale,
        fA, pk1Arr, akArr, cffpArr);

    // ---- primary: persistent kernel (software barrier) ----
    // Guard ONLY on co-residency (deadlock safety); the occupancy API
    // accounts both LDS (35840 B/block => 4 blocks/CU) and VGPRs.
    bool tryPersist = false;
    {
        int occ = 0;
        if (hipOccupancyMaxActiveBlocksPerMultiprocessor(
                &occ, reinterpret_cast<const void*>(persist_kernel), NTHR, 0)
                == hipSuccess) {
            int dev = 0, cu = 0;
            hipGetDevice(&dev);
            hipDeviceGetAttribute(&cu, hipDeviceAttributeMultiprocessorCount, dev);
            if ((long)occ * cu >= NBLK) tryPersist = true;
        }
    }
    if (tryPersist) {
        persist_kernel<<<NBLK, NTHR, 0, stream>>>(
            pk1Arr, akArr, cffpArr, fA, fB, outp, bar);
        return;
    }

    // ---- fallback: 18 compact-streamed launches ----
    for (int t = 0; t < PROP_T; ++t) {
        const float* fin = (t & 1) ? fB : fA;
        float* fout = (t == PROP_T - 1) ? outp : ((t & 1) ? fA : fB);
        step_kernel<<<NPIX / NTHR, NTHR, 0, stream>>>(
            fin, fout, pk1Arr, akArr, cffpArr, (t == PROP_T - 1) ? 1 : 0);
    }
}